// Round 1
// baseline (1060.897 us; speedup 1.0000x reference)
//
#include <hip/hip_runtime.h>
#include <math.h>

constexpr int F = 128;
constexpr int LDA = 132;  // padded LDS stride: 4*132 % 32 == 16 -> 2-way (free); 16B-aligned for float4

// ---------------- CSR build ----------------

__global__ void hist_kernel(const int* __restrict__ dst, int E, int* __restrict__ count) {
    int i = blockIdx.x * blockDim.x + threadIdx.x;
    if (i < E) atomicAdd(&count[dst[i]], 1);
}

__global__ __launch_bounds__(1024) void scan_kernel(const int* __restrict__ count,
                                                    int* __restrict__ row_start,
                                                    int* __restrict__ row_pos,
                                                    int N, int E) {
    __shared__ int tmp[1024];
    int t = threadIdx.x;
    int chunk = (N + 1023) / 1024;
    int lo = t * chunk;
    int hi = min(lo + chunk, N);
    int s = 0;
    for (int i = lo; i < hi; ++i) s += count[i];
    tmp[t] = s;
    __syncthreads();
    for (int d = 1; d < 1024; d <<= 1) {
        int v = (t >= d) ? tmp[t - d] : 0;
        __syncthreads();
        tmp[t] += v;
        __syncthreads();
    }
    int off = tmp[t] - s;  // exclusive prefix
    for (int i = lo; i < hi; ++i) {
        int c = count[i];
        row_start[i] = off;
        row_pos[i] = off;
        off += c;
    }
    if (t == 0) row_start[N] = E;
}

__global__ void scatter_kernel(const int* __restrict__ src, const int* __restrict__ dst,
                               int E, int* __restrict__ row_pos, int* __restrict__ src_sorted) {
    int i = blockIdx.x * blockDim.x + threadIdx.x;
    if (i < E) {
        int p = atomicAdd(&row_pos[dst[i]], 1);
        src_sorted[p] = src[i];
    }
}

// ---------------- aggregation: out[i] = (1+eps)*feat[i] + sum_{j->i} feat[j] ----------------
// one wave per node; lane covers 2 of the 128 features (float2, 512B/row coalesced)

__global__ __launch_bounds__(256) void agg_kernel(const float* __restrict__ feat,
                                                  const int* __restrict__ row_start,
                                                  const int* __restrict__ src_sorted,
                                                  const float* __restrict__ eps_ptr,
                                                  float* __restrict__ out, int N) {
    int wid = (int)((blockIdx.x * blockDim.x + threadIdx.x) >> 6);
    int lane = threadIdx.x & 63;
    if (wid >= N) return;
    int s = row_start[wid];
    int e = row_start[wid + 1];
    float accx = 0.f, accy = 0.f;
    for (int i = s; i < e; ++i) {
        int sv = src_sorted[i];
        float2 v = ((const float2*)(feat + (size_t)sv * F))[lane];
        accx += v.x;
        accy += v.y;
    }
    float ep1 = 1.0f + *eps_ptr;
    float2 self = ((const float2*)(feat + (size_t)wid * F))[lane];
    float2 o;
    o.x = fmaf(ep1, self.x, accx);
    o.y = fmaf(ep1, self.y, accy);
    ((float2*)(out + (size_t)wid * F))[lane] = o;
}

// ---------------- mlp1: out = relu(relu(A@w1 + b1)@w2 + b2), A: N x 128 ----------------
// 64-row tile per block, 256 threads = 16x16 grid, each thread 4 rows x 8 cols

__global__ __launch_bounds__(256) void mlp1_kernel(const float* __restrict__ A,
        const float* __restrict__ w1, const float* __restrict__ b1,
        const float* __restrict__ w2, const float* __restrict__ b2,
        float* __restrict__ out, int N) {
    __shared__ float ldsA[64 * LDA];
    __shared__ float ldsW[32 * 128];
    __shared__ float ldsB[256];
    int t = threadIdx.x;
    int br = blockIdx.x * 64;
    if (t < 128) ldsB[t] = b1[t];
    else         ldsB[t] = b2[t - 128];
    // load A tile (64 x 128)
    for (int i = t; i < 64 * 32; i += 256) {
        int r = i >> 5, c4 = i & 31;
        int gr = br + r;
        float4 v = make_float4(0.f, 0.f, 0.f, 0.f);
        if (gr < N) v = ((const float4*)(A + (size_t)gr * F))[c4];
        *((float4*)&ldsA[r * LDA + c4 * 4]) = v;
    }
    int tx = t & 15, ty = t >> 4;
    int r0 = ty * 4, c0 = tx * 8;
    float acc[4][8];
#pragma unroll
    for (int i = 0; i < 4; ++i)
#pragma unroll
        for (int j = 0; j < 8; ++j) acc[i][j] = 0.f;

    // ---- GEMM1: ldsA @ w1 ----
    for (int kt = 0; kt < 4; ++kt) {
        __syncthreads();  // A stores (kt=0) / previous ldsW reads done
        for (int i = t; i < 32 * 32; i += 256) {
            int r = i >> 5, c4 = i & 31;
            *((float4*)&ldsW[r * 128 + c4 * 4]) =
                ((const float4*)(w1 + (size_t)(kt * 32 + r) * F))[c4];
        }
        __syncthreads();
#pragma unroll
        for (int kk = 0; kk < 32; ++kk) {
            int k = kt * 32 + kk;
            float a0 = ldsA[(r0 + 0) * LDA + k];
            float a1 = ldsA[(r0 + 1) * LDA + k];
            float a2 = ldsA[(r0 + 2) * LDA + k];
            float a3 = ldsA[(r0 + 3) * LDA + k];
            float4 wa = *((const float4*)&ldsW[kk * 128 + c0]);
            float4 wb = *((const float4*)&ldsW[kk * 128 + c0 + 4]);
            float w[8] = {wa.x, wa.y, wa.z, wa.w, wb.x, wb.y, wb.z, wb.w};
#pragma unroll
            for (int j = 0; j < 8; ++j) {
                acc[0][j] = fmaf(a0, w[j], acc[0][j]);
                acc[1][j] = fmaf(a1, w[j], acc[1][j]);
                acc[2][j] = fmaf(a2, w[j], acc[2][j]);
                acc[3][j] = fmaf(a3, w[j], acc[3][j]);
            }
        }
    }
    // relu(acc + b1) -> back into ldsA
    __syncthreads();
#pragma unroll
    for (int i = 0; i < 4; ++i) {
#pragma unroll
        for (int j = 0; j < 8; ++j) {
            float v = acc[i][j] + ldsB[c0 + j];
            ldsA[(r0 + i) * LDA + c0 + j] = v > 0.f ? v : 0.f;
            acc[i][j] = 0.f;
        }
    }
    // ---- GEMM2: ldsA @ w2 ----
    for (int kt = 0; kt < 4; ++kt) {
        __syncthreads();
        for (int i = t; i < 32 * 32; i += 256) {
            int r = i >> 5, c4 = i & 31;
            *((float4*)&ldsW[r * 128 + c4 * 4]) =
                ((const float4*)(w2 + (size_t)(kt * 32 + r) * F))[c4];
        }
        __syncthreads();
#pragma unroll
        for (int kk = 0; kk < 32; ++kk) {
            int k = kt * 32 + kk;
            float a0 = ldsA[(r0 + 0) * LDA + k];
            float a1 = ldsA[(r0 + 1) * LDA + k];
            float a2 = ldsA[(r0 + 2) * LDA + k];
            float a3 = ldsA[(r0 + 3) * LDA + k];
            float4 wa = *((const float4*)&ldsW[kk * 128 + c0]);
            float4 wb = *((const float4*)&ldsW[kk * 128 + c0 + 4]);
            float w[8] = {wa.x, wa.y, wa.z, wa.w, wb.x, wb.y, wb.z, wb.w};
#pragma unroll
            for (int j = 0; j < 8; ++j) {
                acc[0][j] = fmaf(a0, w[j], acc[0][j]);
                acc[1][j] = fmaf(a1, w[j], acc[1][j]);
                acc[2][j] = fmaf(a2, w[j], acc[2][j]);
                acc[3][j] = fmaf(a3, w[j], acc[3][j]);
            }
        }
    }
    // epilogue: relu(acc + b2) -> global
#pragma unroll
    for (int i = 0; i < 4; ++i) {
        int gr = br + r0 + i;
        if (gr < N) {
            float4 o1, o2;
            float v;
            v = acc[i][0] + ldsB[128 + c0 + 0]; o1.x = v > 0.f ? v : 0.f;
            v = acc[i][1] + ldsB[128 + c0 + 1]; o1.y = v > 0.f ? v : 0.f;
            v = acc[i][2] + ldsB[128 + c0 + 2]; o1.z = v > 0.f ? v : 0.f;
            v = acc[i][3] + ldsB[128 + c0 + 3]; o1.w = v > 0.f ? v : 0.f;
            v = acc[i][4] + ldsB[128 + c0 + 4]; o2.x = v > 0.f ? v : 0.f;
            v = acc[i][5] + ldsB[128 + c0 + 5]; o2.y = v > 0.f ? v : 0.f;
            v = acc[i][6] + ldsB[128 + c0 + 6]; o2.z = v > 0.f ? v : 0.f;
            v = acc[i][7] + ldsB[128 + c0 + 7]; o2.w = v > 0.f ? v : 0.f;
            float* p = out + (size_t)gr * F + c0;
            *((float4*)p) = o1;
            *((float4*)(p + 4)) = o2;
        }
    }
}

// ---------------- mlp2: out = log_softmax(relu(A@w3 + b3)@w4 + b4), C=40 ----------------

__global__ __launch_bounds__(256) void mlp2_kernel(const float* __restrict__ A,
        const float* __restrict__ w3, const float* __restrict__ b3,
        const float* __restrict__ w4, const float* __restrict__ b4,
        float* __restrict__ out, int N) {
    __shared__ float ldsA[64 * LDA];
    __shared__ float ldsW[128 * 40];  // union buffer: 32x128 (4096) during gemm3, 128x40 (5120) for w4
    __shared__ float ldsB3[128];
    __shared__ float ldsB4[40];
    int t = threadIdx.x;
    int br = blockIdx.x * 64;
    if (t < 128) ldsB3[t] = b3[t];
    for (int i = t; i < 64 * 32; i += 256) {
        int r = i >> 5, c4 = i & 31;
        int gr = br + r;
        float4 v = make_float4(0.f, 0.f, 0.f, 0.f);
        if (gr < N) v = ((const float4*)(A + (size_t)gr * F))[c4];
        *((float4*)&ldsA[r * LDA + c4 * 4]) = v;
    }
    int tx = t & 15, ty = t >> 4;
    int r0 = ty * 4, c0 = tx * 8;
    float acc[4][8];
#pragma unroll
    for (int i = 0; i < 4; ++i)
#pragma unroll
        for (int j = 0; j < 8; ++j) acc[i][j] = 0.f;

    // ---- GEMM3: ldsA @ w3 ----
    for (int kt = 0; kt < 4; ++kt) {
        __syncthreads();
        for (int i = t; i < 32 * 32; i += 256) {
            int r = i >> 5, c4 = i & 31;
            *((float4*)&ldsW[r * 128 + c4 * 4]) =
                ((const float4*)(w3 + (size_t)(kt * 32 + r) * F))[c4];
        }
        __syncthreads();
#pragma unroll
        for (int kk = 0; kk < 32; ++kk) {
            int k = kt * 32 + kk;
            float a0 = ldsA[(r0 + 0) * LDA + k];
            float a1 = ldsA[(r0 + 1) * LDA + k];
            float a2 = ldsA[(r0 + 2) * LDA + k];
            float a3 = ldsA[(r0 + 3) * LDA + k];
            float4 wa = *((const float4*)&ldsW[kk * 128 + c0]);
            float4 wb = *((const float4*)&ldsW[kk * 128 + c0 + 4]);
            float w[8] = {wa.x, wa.y, wa.z, wa.w, wb.x, wb.y, wb.z, wb.w};
#pragma unroll
            for (int j = 0; j < 8; ++j) {
                acc[0][j] = fmaf(a0, w[j], acc[0][j]);
                acc[1][j] = fmaf(a1, w[j], acc[1][j]);
                acc[2][j] = fmaf(a2, w[j], acc[2][j]);
                acc[3][j] = fmaf(a3, w[j], acc[3][j]);
            }
        }
    }
    // relu(acc + b3) -> back into ldsA
    __syncthreads();
#pragma unroll
    for (int i = 0; i < 4; ++i) {
#pragma unroll
        for (int j = 0; j < 8; ++j) {
            float v = acc[i][j] + ldsB3[c0 + j];
            ldsA[(r0 + i) * LDA + c0 + j] = v > 0.f ? v : 0.f;
        }
    }
    __syncthreads();
    // stage w4 (128x40) + b4
    for (int i = t; i < 128 * 40; i += 256) ldsW[i] = w4[i];
    if (t < 40) ldsB4[t] = b4[t];
    __syncthreads();

    // logits + log_softmax: 4 threads per row, 10 cols each
    int row = t >> 2, q = t & 3;
    float l[10];
#pragma unroll
    for (int j = 0; j < 10; ++j) l[j] = ldsB4[q * 10 + j];
    for (int k = 0; k < 128; ++k) {
        float bv = ldsA[row * LDA + k];
        const float2* wrow = (const float2*)&ldsW[k * 40 + q * 10];
#pragma unroll
        for (int jj = 0; jj < 5; ++jj) {
            float2 wv = wrow[jj];
            l[2 * jj]     = fmaf(bv, wv.x, l[2 * jj]);
            l[2 * jj + 1] = fmaf(bv, wv.y, l[2 * jj + 1]);
        }
    }
    float m = l[0];
#pragma unroll
    for (int j = 1; j < 10; ++j) m = fmaxf(m, l[j]);
    m = fmaxf(m, __shfl_xor(m, 1));
    m = fmaxf(m, __shfl_xor(m, 2));
    float ssum = 0.f;
#pragma unroll
    for (int j = 0; j < 10; ++j) ssum += expf(l[j] - m);
    ssum += __shfl_xor(ssum, 1);
    ssum += __shfl_xor(ssum, 2);
    float L = m + logf(ssum);
    int gr = br + row;
    if (gr < N) {
        float* p = out + (size_t)gr * 40 + q * 10;
#pragma unroll
        for (int j = 0; j < 10; ++j) p[j] = l[j] - L;
    }
}

// ---------------- launch ----------------

extern "C" void kernel_launch(void* const* d_in, const int* in_sizes, int n_in,
                              void* d_out, int out_size, void* d_ws, size_t ws_size,
                              hipStream_t stream) {
    const float* x    = (const float*)d_in[0];
    const int*   ei   = (const int*)d_in[1];
    const float* eps1 = (const float*)d_in[2];
    const float* w1   = (const float*)d_in[3];
    const float* b1   = (const float*)d_in[4];
    const float* w2   = (const float*)d_in[5];
    const float* b2   = (const float*)d_in[6];
    const float* eps2 = (const float*)d_in[7];
    const float* w3   = (const float*)d_in[8];
    const float* b3   = (const float*)d_in[9];
    const float* w4   = (const float*)d_in[10];
    const float* b4   = (const float*)d_in[11];
    float* out = (float*)d_out;

    int N = in_sizes[0] / F;       // 100000
    int E = in_sizes[1] / 2;       // 1600000
    const int* src = ei;           // edge_index[0]
    const int* dst = ei + E;       // edge_index[1]

    // workspace layout
    float* h0 = (float*)d_ws;                       // N*128 floats
    float* h  = h0 + (size_t)N * F;                 // N*128 floats
    int* ibase      = (int*)(h + (size_t)N * F);
    int* count      = ibase;                        // N
    int* row_start  = count + N;                    // N+1
    int* row_pos    = row_start + (N + 1);          // N
    int* src_sorted = row_pos + N;                  // E

    // CSR build
    hipMemsetAsync(count, 0, (size_t)N * sizeof(int), stream);
    hist_kernel<<<(E + 255) / 256, 256, 0, stream>>>(dst, E, count);
    scan_kernel<<<1, 1024, 0, stream>>>(count, row_start, row_pos, N, E);
    scatter_kernel<<<(E + 255) / 256, 256, 0, stream>>>(src, dst, E, row_pos, src_sorted);

    // layer 1
    agg_kernel<<<(N + 3) / 4, 256, 0, stream>>>(x, row_start, src_sorted, eps1, h0, N);
    mlp1_kernel<<<(N + 63) / 64, 256, 0, stream>>>(h0, w1, b1, w2, b2, h, N);
    // layer 2
    agg_kernel<<<(N + 3) / 4, 256, 0, stream>>>(h, row_start, src_sorted, eps2, h0, N);
    mlp2_kernel<<<(N + 63) / 64, 256, 0, stream>>>(h0, w3, b3, w4, b4, out, N);
}

// Round 2
// 742.520 us; speedup vs baseline: 1.4288x; 1.4288x over previous
//
#include <hip/hip_runtime.h>
#include <math.h>

constexpr int F = 128;
constexpr int LDA = 132;  // padded LDS stride: 4*132 % 32 == 16 -> 2-way (free); 16B-aligned for float4
constexpr int SCAN_TILE = 1024;  // elements per scan block (256 thr x int4)

// ---------------- CSR build ----------------

__global__ void hist_kernel(const int* __restrict__ dst, int E, int* __restrict__ count) {
    int i = blockIdx.x * blockDim.x + threadIdx.x;
    if (i < E) atomicAdd(&count[dst[i]], 1);
}

// stage 1: per-block sums of count[] (1024 elements / block)
__global__ __launch_bounds__(256) void scan_reduce_kernel(const int* __restrict__ count, int N,
                                                          int* __restrict__ partials) {
    __shared__ int red[256];
    int t = threadIdx.x;
    int base = blockIdx.x * SCAN_TILE + t * 4;
    int s = 0;
    if (base + 3 < N) {
        int4 c = *((const int4*)(count + base));
        s = c.x + c.y + c.z + c.w;
    } else {
        for (int j = 0; j < 4; ++j) if (base + j < N) s += count[base + j];
    }
    red[t] = s;
    __syncthreads();
    for (int d = 128; d > 0; d >>= 1) {
        if (t < d) red[t] += red[t + d];
        __syncthreads();
    }
    if (t == 0) partials[blockIdx.x] = red[0];
}

// stage 2: single small block scans the partials (B1 <= 256)
__global__ __launch_bounds__(256) void scan_partials_kernel(int* __restrict__ partials, int B1,
                                                            int* __restrict__ partials_ex,
                                                            int* __restrict__ row_start, int N, int E) {
    __shared__ int tmp[256];
    int t = threadIdx.x;
    int v = (t < B1) ? partials[t] : 0;
    tmp[t] = v;
    __syncthreads();
    for (int d = 1; d < 256; d <<= 1) {
        int add = (t >= d) ? tmp[t - d] : 0;
        __syncthreads();
        tmp[t] += add;
        __syncthreads();
    }
    if (t < B1) partials_ex[t] = tmp[t] - v;  // exclusive
    if (t == 0) row_start[N] = E;
}

// stage 3: rescan each block's 1024 elements, add block offset, write row_start + row_pos
__global__ __launch_bounds__(256) void scan_write_kernel(const int* __restrict__ count, int N,
                                                         const int* __restrict__ partials_ex,
                                                         int* __restrict__ row_start,
                                                         int* __restrict__ row_pos) {
    __shared__ int tmp[256];
    int t = threadIdx.x;
    int base = blockIdx.x * SCAN_TILE + t * 4;
    int4 c = make_int4(0, 0, 0, 0);
    if (base + 3 < N) {
        c = *((const int4*)(count + base));
    } else {
        if (base + 0 < N) c.x = count[base + 0];
        if (base + 1 < N) c.y = count[base + 1];
        if (base + 2 < N) c.z = count[base + 2];
        if (base + 3 < N) c.w = count[base + 3];
    }
    int s = c.x + c.y + c.z + c.w;
    tmp[t] = s;
    __syncthreads();
    for (int d = 1; d < 256; d <<= 1) {
        int add = (t >= d) ? tmp[t - d] : 0;
        __syncthreads();
        tmp[t] += add;
        __syncthreads();
    }
    int off = tmp[t] - s + partials_ex[blockIdx.x];
    int e0 = off, e1 = off + c.x, e2 = e1 + c.y, e3 = e2 + c.z;
    if (base + 0 < N) { row_start[base + 0] = e0; row_pos[base + 0] = e0; }
    if (base + 1 < N) { row_start[base + 1] = e1; row_pos[base + 1] = e1; }
    if (base + 2 < N) { row_start[base + 2] = e2; row_pos[base + 2] = e2; }
    if (base + 3 < N) { row_start[base + 3] = e3; row_pos[base + 3] = e3; }
}

__global__ void scatter_kernel(const int* __restrict__ src, const int* __restrict__ dst,
                               int E, int* __restrict__ row_pos, int* __restrict__ src_sorted) {
    int i = blockIdx.x * blockDim.x + threadIdx.x;
    if (i < E) {
        int p = atomicAdd(&row_pos[dst[i]], 1);
        src_sorted[p] = src[i];
    }
}

// ---------------- aggregation: out[i] = (1+eps)*feat[i] + sum_{j->i} feat[j] ----------------
// one wave per node; wave split into two 32-lane halves, each half covers the full 128-feat row
// via float4/lane and processes alternate edges; 2x unroll -> 4 independent 512B gathers in flight

__global__ __launch_bounds__(256) void agg_kernel(const float* __restrict__ feat,
                                                  const int* __restrict__ row_start,
                                                  const int* __restrict__ src_sorted,
                                                  const float* __restrict__ eps_ptr,
                                                  float* __restrict__ out, int N) {
    int wid = (int)((blockIdx.x * blockDim.x + threadIdx.x) >> 6);
    int lane = threadIdx.x & 63;
    if (wid >= N) return;
    int half = lane >> 5;     // 0 or 1
    int l32 = lane & 31;      // float4 chunk index within row
    int s = row_start[wid];
    int e = row_start[wid + 1];
    float4 acc0 = make_float4(0.f, 0.f, 0.f, 0.f);
    float4 acc1 = make_float4(0.f, 0.f, 0.f, 0.f);
    int i = s + half;
    for (; i + 2 < e; i += 4) {
        int sv0 = src_sorted[i];
        int sv1 = src_sorted[i + 2];
        float4 v0 = ((const float4*)(feat + (size_t)sv0 * F))[l32];
        float4 v1 = ((const float4*)(feat + (size_t)sv1 * F))[l32];
        acc0.x += v0.x; acc0.y += v0.y; acc0.z += v0.z; acc0.w += v0.w;
        acc1.x += v1.x; acc1.y += v1.y; acc1.z += v1.z; acc1.w += v1.w;
    }
    if (i < e) {
        int sv = src_sorted[i];
        float4 v = ((const float4*)(feat + (size_t)sv * F))[l32];
        acc0.x += v.x; acc0.y += v.y; acc0.z += v.z; acc0.w += v.w;
    }
    acc0.x += acc1.x; acc0.y += acc1.y; acc0.z += acc1.z; acc0.w += acc1.w;
    // combine the two halves (xor 32)
    acc0.x += __shfl_xor(acc0.x, 32);
    acc0.y += __shfl_xor(acc0.y, 32);
    acc0.z += __shfl_xor(acc0.z, 32);
    acc0.w += __shfl_xor(acc0.w, 32);
    if (half == 0) {
        float ep1 = 1.0f + *eps_ptr;
        float4 self = ((const float4*)(feat + (size_t)wid * F))[l32];
        float4 o;
        o.x = fmaf(ep1, self.x, acc0.x);
        o.y = fmaf(ep1, self.y, acc0.y);
        o.z = fmaf(ep1, self.z, acc0.z);
        o.w = fmaf(ep1, self.w, acc0.w);
        ((float4*)(out + (size_t)wid * F))[l32] = o;
    }
}

// ---------------- mlp1: out = relu(relu(A@w1 + b1)@w2 + b2), A: N x 128 ----------------
// 64-row tile per block, 256 threads = 16x16 grid, each thread 4 rows x 8 cols

__global__ __launch_bounds__(256) void mlp1_kernel(const float* __restrict__ A,
        const float* __restrict__ w1, const float* __restrict__ b1,
        const float* __restrict__ w2, const float* __restrict__ b2,
        float* __restrict__ out, int N) {
    __shared__ float ldsA[64 * LDA];
    __shared__ float ldsW[32 * 128];
    __shared__ float ldsB[256];
    int t = threadIdx.x;
    int br = blockIdx.x * 64;
    if (t < 128) ldsB[t] = b1[t];
    else         ldsB[t] = b2[t - 128];
    // load A tile (64 x 128)
    for (int i = t; i < 64 * 32; i += 256) {
        int r = i >> 5, c4 = i & 31;
        int gr = br + r;
        float4 v = make_float4(0.f, 0.f, 0.f, 0.f);
        if (gr < N) v = ((const float4*)(A + (size_t)gr * F))[c4];
        *((float4*)&ldsA[r * LDA + c4 * 4]) = v;
    }
    int tx = t & 15, ty = t >> 4;
    int r0 = ty * 4, c0 = tx * 8;
    float acc[4][8];
#pragma unroll
    for (int i = 0; i < 4; ++i)
#pragma unroll
        for (int j = 0; j < 8; ++j) acc[i][j] = 0.f;

    // ---- GEMM1: ldsA @ w1 ----
    for (int kt = 0; kt < 4; ++kt) {
        __syncthreads();  // A stores (kt=0) / previous ldsW reads done
        for (int i = t; i < 32 * 32; i += 256) {
            int r = i >> 5, c4 = i & 31;
            *((float4*)&ldsW[r * 128 + c4 * 4]) =
                ((const float4*)(w1 + (size_t)(kt * 32 + r) * F))[c4];
        }
        __syncthreads();
#pragma unroll
        for (int kk = 0; kk < 32; ++kk) {
            int k = kt * 32 + kk;
            float a0 = ldsA[(r0 + 0) * LDA + k];
            float a1 = ldsA[(r0 + 1) * LDA + k];
            float a2 = ldsA[(r0 + 2) * LDA + k];
            float a3 = ldsA[(r0 + 3) * LDA + k];
            float4 wa = *((const float4*)&ldsW[kk * 128 + c0]);
            float4 wb = *((const float4*)&ldsW[kk * 128 + c0 + 4]);
            float w[8] = {wa.x, wa.y, wa.z, wa.w, wb.x, wb.y, wb.z, wb.w};
#pragma unroll
            for (int j = 0; j < 8; ++j) {
                acc[0][j] = fmaf(a0, w[j], acc[0][j]);
                acc[1][j] = fmaf(a1, w[j], acc[1][j]);
                acc[2][j] = fmaf(a2, w[j], acc[2][j]);
                acc[3][j] = fmaf(a3, w[j], acc[3][j]);
            }
        }
    }
    // relu(acc + b1) -> back into ldsA
    __syncthreads();
#pragma unroll
    for (int i = 0; i < 4; ++i) {
#pragma unroll
        for (int j = 0; j < 8; ++j) {
            float v = acc[i][j] + ldsB[c0 + j];
            ldsA[(r0 + i) * LDA + c0 + j] = v > 0.f ? v : 0.f;
            acc[i][j] = 0.f;
        }
    }
    // ---- GEMM2: ldsA @ w2 ----
    for (int kt = 0; kt < 4; ++kt) {
        __syncthreads();
        for (int i = t; i < 32 * 32; i += 256) {
            int r = i >> 5, c4 = i & 31;
            *((float4*)&ldsW[r * 128 + c4 * 4]) =
                ((const float4*)(w2 + (size_t)(kt * 32 + r) * F))[c4];
        }
        __syncthreads();
#pragma unroll
        for (int kk = 0; kk < 32; ++kk) {
            int k = kt * 32 + kk;
            float a0 = ldsA[(r0 + 0) * LDA + k];
            float a1 = ldsA[(r0 + 1) * LDA + k];
            float a2 = ldsA[(r0 + 2) * LDA + k];
            float a3 = ldsA[(r0 + 3) * LDA + k];
            float4 wa = *((const float4*)&ldsW[kk * 128 + c0]);
            float4 wb = *((const float4*)&ldsW[kk * 128 + c0 + 4]);
            float w[8] = {wa.x, wa.y, wa.z, wa.w, wb.x, wb.y, wb.z, wb.w};
#pragma unroll
            for (int j = 0; j < 8; ++j) {
                acc[0][j] = fmaf(a0, w[j], acc[0][j]);
                acc[1][j] = fmaf(a1, w[j], acc[1][j]);
                acc[2][j] = fmaf(a2, w[j], acc[2][j]);
                acc[3][j] = fmaf(a3, w[j], acc[3][j]);
            }
        }
    }
    // epilogue: relu(acc + b2) -> global
#pragma unroll
    for (int i = 0; i < 4; ++i) {
        int gr = br + r0 + i;
        if (gr < N) {
            float4 o1, o2;
            float v;
            v = acc[i][0] + ldsB[128 + c0 + 0]; o1.x = v > 0.f ? v : 0.f;
            v = acc[i][1] + ldsB[128 + c0 + 1]; o1.y = v > 0.f ? v : 0.f;
            v = acc[i][2] + ldsB[128 + c0 + 2]; o1.z = v > 0.f ? v : 0.f;
            v = acc[i][3] + ldsB[128 + c0 + 3]; o1.w = v > 0.f ? v : 0.f;
            v = acc[i][4] + ldsB[128 + c0 + 4]; o2.x = v > 0.f ? v : 0.f;
            v = acc[i][5] + ldsB[128 + c0 + 5]; o2.y = v > 0.f ? v : 0.f;
            v = acc[i][6] + ldsB[128 + c0 + 6]; o2.z = v > 0.f ? v : 0.f;
            v = acc[i][7] + ldsB[128 + c0 + 7]; o2.w = v > 0.f ? v : 0.f;
            float* p = out + (size_t)gr * F + c0;
            *((float4*)p) = o1;
            *((float4*)(p + 4)) = o2;
        }
    }
}

// ---------------- mlp2: out = log_softmax(relu(A@w3 + b3)@w4 + b4), C=40 ----------------

__global__ __launch_bounds__(256) void mlp2_kernel(const float* __restrict__ A,
        const float* __restrict__ w3, const float* __restrict__ b3,
        const float* __restrict__ w4, const float* __restrict__ b4,
        float* __restrict__ out, int N) {
    __shared__ float ldsA[64 * LDA];
    __shared__ float ldsW[128 * 40];  // union buffer: 32x128 (4096) during gemm3, 128x40 (5120) for w4
    __shared__ float ldsB3[128];
    __shared__ float ldsB4[40];
    int t = threadIdx.x;
    int br = blockIdx.x * 64;
    if (t < 128) ldsB3[t] = b3[t];
    for (int i = t; i < 64 * 32; i += 256) {
        int r = i >> 5, c4 = i & 31;
        int gr = br + r;
        float4 v = make_float4(0.f, 0.f, 0.f, 0.f);
        if (gr < N) v = ((const float4*)(A + (size_t)gr * F))[c4];
        *((float4*)&ldsA[r * LDA + c4 * 4]) = v;
    }
    int tx = t & 15, ty = t >> 4;
    int r0 = ty * 4, c0 = tx * 8;
    float acc[4][8];
#pragma unroll
    for (int i = 0; i < 4; ++i)
#pragma unroll
        for (int j = 0; j < 8; ++j) acc[i][j] = 0.f;

    // ---- GEMM3: ldsA @ w3 ----
    for (int kt = 0; kt < 4; ++kt) {
        __syncthreads();
        for (int i = t; i < 32 * 32; i += 256) {
            int r = i >> 5, c4 = i & 31;
            *((float4*)&ldsW[r * 128 + c4 * 4]) =
                ((const float4*)(w3 + (size_t)(kt * 32 + r) * F))[c4];
        }
        __syncthreads();
#pragma unroll
        for (int kk = 0; kk < 32; ++kk) {
            int k = kt * 32 + kk;
            float a0 = ldsA[(r0 + 0) * LDA + k];
            float a1 = ldsA[(r0 + 1) * LDA + k];
            float a2 = ldsA[(r0 + 2) * LDA + k];
            float a3 = ldsA[(r0 + 3) * LDA + k];
            float4 wa = *((const float4*)&ldsW[kk * 128 + c0]);
            float4 wb = *((const float4*)&ldsW[kk * 128 + c0 + 4]);
            float w[8] = {wa.x, wa.y, wa.z, wa.w, wb.x, wb.y, wb.z, wb.w};
#pragma unroll
            for (int j = 0; j < 8; ++j) {
                acc[0][j] = fmaf(a0, w[j], acc[0][j]);
                acc[1][j] = fmaf(a1, w[j], acc[1][j]);
                acc[2][j] = fmaf(a2, w[j], acc[2][j]);
                acc[3][j] = fmaf(a3, w[j], acc[3][j]);
            }
        }
    }
    // relu(acc + b3) -> back into ldsA
    __syncthreads();
#pragma unroll
    for (int i = 0; i < 4; ++i) {
#pragma unroll
        for (int j = 0; j < 8; ++j) {
            float v = acc[i][j] + ldsB3[c0 + j];
            ldsA[(r0 + i) * LDA + c0 + j] = v > 0.f ? v : 0.f;
        }
    }
    __syncthreads();
    // stage w4 (128x40) + b4
    for (int i = t; i < 128 * 40; i += 256) ldsW[i] = w4[i];
    if (t < 40) ldsB4[t] = b4[t];
    __syncthreads();

    // logits + log_softmax: 4 threads per row, 10 cols each
    int row = t >> 2, q = t & 3;
    float l[10];
#pragma unroll
    for (int j = 0; j < 10; ++j) l[j] = ldsB4[q * 10 + j];
    for (int k = 0; k < 128; ++k) {
        float bv = ldsA[row * LDA + k];
        const float2* wrow = (const float2*)&ldsW[k * 40 + q * 10];
#pragma unroll
        for (int jj = 0; jj < 5; ++jj) {
            float2 wv = wrow[jj];
            l[2 * jj]     = fmaf(bv, wv.x, l[2 * jj]);
            l[2 * jj + 1] = fmaf(bv, wv.y, l[2 * jj + 1]);
        }
    }
    float m = l[0];
#pragma unroll
    for (int j = 1; j < 10; ++j) m = fmaxf(m, l[j]);
    m = fmaxf(m, __shfl_xor(m, 1));
    m = fmaxf(m, __shfl_xor(m, 2));
    float ssum = 0.f;
#pragma unroll
    for (int j = 0; j < 10; ++j) ssum += expf(l[j] - m);
    ssum += __shfl_xor(ssum, 1);
    ssum += __shfl_xor(ssum, 2);
    float L = m + logf(ssum);
    int gr = br + row;
    if (gr < N) {
        float* p = out + (size_t)gr * 40 + q * 10;
#pragma unroll
        for (int j = 0; j < 10; ++j) p[j] = l[j] - L;
    }
}

// ---------------- launch ----------------

extern "C" void kernel_launch(void* const* d_in, const int* in_sizes, int n_in,
                              void* d_out, int out_size, void* d_ws, size_t ws_size,
                              hipStream_t stream) {
    const float* x    = (const float*)d_in[0];
    const int*   ei   = (const int*)d_in[1];
    const float* eps1 = (const float*)d_in[2];
    const float* w1   = (const float*)d_in[3];
    const float* b1   = (const float*)d_in[4];
    const float* w2   = (const float*)d_in[5];
    const float* b2   = (const float*)d_in[6];
    const float* eps2 = (const float*)d_in[7];
    const float* w3   = (const float*)d_in[8];
    const float* b3   = (const float*)d_in[9];
    const float* w4   = (const float*)d_in[10];
    const float* b4   = (const float*)d_in[11];
    float* out = (float*)d_out;

    int N = in_sizes[0] / F;       // 100000
    int E = in_sizes[1] / 2;       // 1600000
    const int* src = ei;           // edge_index[0]
    const int* dst = ei + E;       // edge_index[1]

    int B1 = (N + SCAN_TILE - 1) / SCAN_TILE;  // 98 scan blocks (<= 256 required)

    // workspace layout
    float* h0 = (float*)d_ws;                       // N*128 floats
    float* h  = h0 + (size_t)N * F;                 // N*128 floats
    int* ibase       = (int*)(h + (size_t)N * F);
    int* count       = ibase;                       // N
    int* row_start   = count + N;                   // N+1
    int* row_pos     = row_start + (N + 1);         // N
    int* src_sorted  = row_pos + N;                 // E
    int* partials    = src_sorted + E;              // 256
    int* partials_ex = partials + 256;              // 256

    // CSR build (hierarchical scan)
    hipMemsetAsync(count, 0, (size_t)N * sizeof(int), stream);
    hist_kernel<<<(E + 255) / 256, 256, 0, stream>>>(dst, E, count);
    scan_reduce_kernel<<<B1, 256, 0, stream>>>(count, N, partials);
    scan_partials_kernel<<<1, 256, 0, stream>>>(partials, B1, partials_ex, row_start, N, E);
    scan_write_kernel<<<B1, 256, 0, stream>>>(count, N, partials_ex, row_start, row_pos);
    scatter_kernel<<<(E + 255) / 256, 256, 0, stream>>>(src, dst, E, row_pos, src_sorted);

    // layer 1
    agg_kernel<<<(N + 3) / 4, 256, 0, stream>>>(x, row_start, src_sorted, eps1, h0, N);
    mlp1_kernel<<<(N + 63) / 64, 256, 0, stream>>>(h0, w1, b1, w2, b2, h, N);
    // layer 2
    agg_kernel<<<(N + 3) / 4, 256, 0, stream>>>(h, row_start, src_sorted, eps2, h0, N);
    mlp2_kernel<<<(N + 63) / 64, 256, 0, stream>>>(h0, w3, b3, w4, b4, out, N);
}

// Round 3
// 505.274 us; speedup vs baseline: 2.0996x; 1.4695x over previous
//
#include <hip/hip_runtime.h>
#include <hip/hip_fp16.h>
#include <math.h>

constexpr int F = 128;
constexpr int C = 40;
constexpr int SCAN_TILE = 1024;
constexpr int LDH = 136;  // padded LDS stride in halves: 272B = 68 words -> bank rotation 4

typedef __attribute__((ext_vector_type(8))) _Float16 half8;
typedef __attribute__((ext_vector_type(4))) float float4v;

// ---------------- CSR build ----------------

__global__ void hist_kernel(const int* __restrict__ dst, int E, int* __restrict__ count) {
    int i = blockIdx.x * blockDim.x + threadIdx.x;
    if (i < E) atomicAdd(&count[dst[i]], 1);
}

__global__ __launch_bounds__(256) void scan_reduce_kernel(const int* __restrict__ count, int N,
                                                          int* __restrict__ partials) {
    __shared__ int red[256];
    int t = threadIdx.x;
    int base = blockIdx.x * SCAN_TILE + t * 4;
    int s = 0;
    if (base + 3 < N) {
        int4 c = *((const int4*)(count + base));
        s = c.x + c.y + c.z + c.w;
    } else {
        for (int j = 0; j < 4; ++j) if (base + j < N) s += count[base + j];
    }
    red[t] = s;
    __syncthreads();
    for (int d = 128; d > 0; d >>= 1) {
        if (t < d) red[t] += red[t + d];
        __syncthreads();
    }
    if (t == 0) partials[blockIdx.x] = red[0];
}

__global__ __launch_bounds__(256) void scan_partials_kernel(int* __restrict__ partials, int B1,
                                                            int* __restrict__ partials_ex,
                                                            int* __restrict__ row_start, int N, int E) {
    __shared__ int tmp[256];
    int t = threadIdx.x;
    int v = (t < B1) ? partials[t] : 0;
    tmp[t] = v;
    __syncthreads();
    for (int d = 1; d < 256; d <<= 1) {
        int add = (t >= d) ? tmp[t - d] : 0;
        __syncthreads();
        tmp[t] += add;
        __syncthreads();
    }
    if (t < B1) partials_ex[t] = tmp[t] - v;
    if (t == 0) row_start[N] = E;
}

__global__ __launch_bounds__(256) void scan_write_kernel(const int* __restrict__ count, int N,
                                                         const int* __restrict__ partials_ex,
                                                         int* __restrict__ row_start,
                                                         int* __restrict__ row_pos) {
    __shared__ int tmp[256];
    int t = threadIdx.x;
    int base = blockIdx.x * SCAN_TILE + t * 4;
    int4 c = make_int4(0, 0, 0, 0);
    if (base + 3 < N) {
        c = *((const int4*)(count + base));
    } else {
        if (base + 0 < N) c.x = count[base + 0];
        if (base + 1 < N) c.y = count[base + 1];
        if (base + 2 < N) c.z = count[base + 2];
        if (base + 3 < N) c.w = count[base + 3];
    }
    int s = c.x + c.y + c.z + c.w;
    tmp[t] = s;
    __syncthreads();
    for (int d = 1; d < 256; d <<= 1) {
        int add = (t >= d) ? tmp[t - d] : 0;
        __syncthreads();
        tmp[t] += add;
        __syncthreads();
    }
    int off = tmp[t] - s + partials_ex[blockIdx.x];
    int e0 = off, e1 = off + c.x, e2 = e1 + c.y, e3 = e2 + c.z;
    if (base + 0 < N) { row_start[base + 0] = e0; row_pos[base + 0] = e0; }
    if (base + 1 < N) { row_start[base + 1] = e1; row_pos[base + 1] = e1; }
    if (base + 2 < N) { row_start[base + 2] = e2; row_pos[base + 2] = e2; }
    if (base + 3 < N) { row_start[base + 3] = e3; row_pos[base + 3] = e3; }
}

__global__ void scatter_kernel(const int* __restrict__ src, const int* __restrict__ dst,
                               int E, int* __restrict__ row_pos, int* __restrict__ src_sorted) {
    int i = blockIdx.x * blockDim.x + threadIdx.x;
    if (i < E) {
        int p = atomicAdd(&row_pos[dst[i]], 1);
        src_sorted[p] = src[i];
    }
}

// ---------------- prep: fp32 -> fp16 feature copy ----------------

__global__ void conv_f16_kernel(const float* __restrict__ in, __half* __restrict__ out, int n4) {
    int i = blockIdx.x * blockDim.x + threadIdx.x;
    if (i >= n4) return;
    float4 v = ((const float4*)in)[i];
    __half2 a = __floats2half2_rn(v.x, v.y);
    __half2 b = __floats2half2_rn(v.z, v.w);
    uint2 o;
    o.x = __builtin_bit_cast(unsigned, a);
    o.y = __builtin_bit_cast(unsigned, b);
    ((uint2*)out)[i] = o;
}

// ---------------- prep: weight transpose fp32 [K=128][Nin] -> fp16 [Npad][128] ----------------

__global__ __launch_bounds__(256) void prep_weights_kernel(
        const float* __restrict__ w1, const float* __restrict__ w2,
        const float* __restrict__ w3, const float* __restrict__ w4,
        __half* __restrict__ w1t, __half* __restrict__ w2t,
        __half* __restrict__ w3t, __half* __restrict__ w4t) {
    __shared__ float lds[128 * 128];
    const float* in; __half* outp; int Nin, Npad;
    switch (blockIdx.x) {
        case 0:  in = w1; outp = w1t; Nin = 128; Npad = 128; break;
        case 1:  in = w2; outp = w2t; Nin = 128; Npad = 128; break;
        case 2:  in = w3; outp = w3t; Nin = 128; Npad = 128; break;
        default: in = w4; outp = w4t; Nin = 40;  Npad = 48;  break;
    }
    int t = threadIdx.x;
    int nf4 = 128 * Nin / 4;
    for (int i = t; i < nf4; i += 256)
        ((float4*)lds)[i] = ((const float4*)in)[i];
    __syncthreads();
    int total = Npad * 64;  // half2 count
    for (int i = t; i < total; i += 256) {
        int n = i >> 6, k2 = (i & 63) * 2;
        float lo = 0.f, hi = 0.f;
        if (n < Nin) {
            lo = lds[k2 * Nin + n];
            hi = lds[(k2 + 1) * Nin + n];
        }
        __half2 h = __floats2half2_rn(lo, hi);
        ((unsigned*)outp)[i] = __builtin_bit_cast(unsigned, h);
    }
}

// ---------------- aggregation (fp16 feat, fp32 accumulate) ----------------
// one wave per node; two 32-lane halves each cover the full 128-feat row (uint2 = 4 halves/lane)

__global__ __launch_bounds__(256) void agg_f16_kernel(const __half* __restrict__ feat,
        const int* __restrict__ row_start, const int* __restrict__ src_sorted,
        const float* __restrict__ eps_ptr, __half* __restrict__ out, int N) {
    int wid = (int)((blockIdx.x * blockDim.x + threadIdx.x) >> 6);
    int lane = threadIdx.x & 63;
    if (wid >= N) return;
    int hf = lane >> 5, l32 = lane & 31;
    int s = row_start[wid], e = row_start[wid + 1];
    float a0 = 0.f, a1 = 0.f, a2 = 0.f, a3 = 0.f;
    float b0 = 0.f, b1 = 0.f, b2 = 0.f, b3 = 0.f;
    int i = s + hf;
    for (; i + 2 < e; i += 4) {
        int sv0 = src_sorted[i];
        int sv1 = src_sorted[i + 2];
        uint2 u0 = *(((const uint2*)(feat + (size_t)sv0 * F)) + l32);
        uint2 u1 = *(((const uint2*)(feat + (size_t)sv1 * F)) + l32);
        float2 f0 = __half22float2(__builtin_bit_cast(__half2, u0.x));
        float2 f1 = __half22float2(__builtin_bit_cast(__half2, u0.y));
        float2 f2 = __half22float2(__builtin_bit_cast(__half2, u1.x));
        float2 f3 = __half22float2(__builtin_bit_cast(__half2, u1.y));
        a0 += f0.x; a1 += f0.y; a2 += f1.x; a3 += f1.y;
        b0 += f2.x; b1 += f2.y; b2 += f3.x; b3 += f3.y;
    }
    if (i < e) {
        int sv = src_sorted[i];
        uint2 u = *(((const uint2*)(feat + (size_t)sv * F)) + l32);
        float2 f0 = __half22float2(__builtin_bit_cast(__half2, u.x));
        float2 f1 = __half22float2(__builtin_bit_cast(__half2, u.y));
        a0 += f0.x; a1 += f0.y; a2 += f1.x; a3 += f1.y;
    }
    a0 += b0; a1 += b1; a2 += b2; a3 += b3;
    a0 += __shfl_xor(a0, 32);
    a1 += __shfl_xor(a1, 32);
    a2 += __shfl_xor(a2, 32);
    a3 += __shfl_xor(a3, 32);
    if (hf == 0) {
        float ep1 = 1.0f + *eps_ptr;
        uint2 u = *(((const uint2*)(feat + (size_t)wid * F)) + l32);
        float2 s0 = __half22float2(__builtin_bit_cast(__half2, u.x));
        float2 s1 = __half22float2(__builtin_bit_cast(__half2, u.y));
        a0 = fmaf(ep1, s0.x, a0);
        a1 = fmaf(ep1, s0.y, a1);
        a2 = fmaf(ep1, s1.x, a2);
        a3 = fmaf(ep1, s1.y, a3);
        __half2 o0 = __floats2half2_rn(a0, a1);
        __half2 o1 = __floats2half2_rn(a2, a3);
        uint2 ou;
        ou.x = __builtin_bit_cast(unsigned, o0);
        ou.y = __builtin_bit_cast(unsigned, o1);
        *(((uint2*)(out + (size_t)wid * F)) + l32) = ou;
    }
}

// ---------------- mlp1 (MFMA): out = relu(relu(A@w1+b1)@w2+b2), fp16 in/out ----------------
// 64 nodes/block, 4 waves. MFMA operands: A-op = wT[n][k] frag, B-op = act[node][k] frag.
// D[outcol][node]: lane holds out[node=i*16+l16][outcol=c*16+quad*4+r].

__global__ __launch_bounds__(256) void mlp1_mfma_kernel(const __half* __restrict__ A,
        const __half* __restrict__ w1t, const float* __restrict__ b1,
        const __half* __restrict__ w2t, const float* __restrict__ b2,
        __half* __restrict__ out, int N) {
    __shared__ __half ldsA[64 * LDH];
    __shared__ __half ldsW[128 * LDH];
    __shared__ float ldsB[256];
    int t = threadIdx.x;
    int wave = t >> 6, lane = t & 63, quad = lane >> 4, l16 = lane & 15;
    int br = blockIdx.x * 64;
    if (t < 128) ldsB[t] = b1[t];
    else         ldsB[t] = b2[t - 128];
    for (int i = t; i < 1024; i += 256) {  // A tile: 64 rows x 8 chunks(16B)... 16 chunks
        int r = i >> 4, c = i & 15;
        int gr = br + r;
        uint4 v = make_uint4(0u, 0u, 0u, 0u);
        if (gr < N) v = *((const uint4*)(A + (size_t)gr * F + c * 8));
        *((uint4*)&ldsA[r * LDH + c * 8]) = v;
    }
    for (int i = t; i < 2048; i += 256) {  // w1t: 128 rows x 16 chunks
        int r = i >> 4, c = i & 15;
        *((uint4*)&ldsW[r * LDH + c * 8]) = *((const uint4*)(w1t + r * 128 + c * 8));
    }
    __syncthreads();

    int ct0 = wave * 2;
    float4v acc[4][2];
    float4v zero = {0.f, 0.f, 0.f, 0.f};
#pragma unroll
    for (int i = 0; i < 4; ++i)
#pragma unroll
        for (int j = 0; j < 2; ++j) acc[i][j] = zero;

    // ---- GEMM1 ----
#pragma unroll
    for (int ks = 0; ks < 4; ++ks) {
        half8 af[4], wf[2];
#pragma unroll
        for (int i = 0; i < 4; ++i)
            af[i] = *((const half8*)&ldsA[(i * 16 + l16) * LDH + ks * 32 + quad * 8]);
#pragma unroll
        for (int j = 0; j < 2; ++j)
            wf[j] = *((const half8*)&ldsW[((ct0 + j) * 16 + l16) * LDH + ks * 32 + quad * 8]);
#pragma unroll
        for (int i = 0; i < 4; ++i)
#pragma unroll
            for (int j = 0; j < 2; ++j)
                acc[i][j] = __builtin_amdgcn_mfma_f32_16x16x32_f16(wf[j], af[i], acc[i][j], 0, 0, 0);
    }
    __syncthreads();
    // mid: relu(acc+b1) -> ldsA (fp16), stage w2t -> ldsW
#pragma unroll
    for (int j = 0; j < 2; ++j) {
        int c = ct0 + j;
        float4 bb = *((const float4*)&ldsB[c * 16 + quad * 4]);
#pragma unroll
        for (int i = 0; i < 4; ++i) {
            float v0 = acc[i][j][0] + bb.x; v0 = v0 > 0.f ? v0 : 0.f;
            float v1 = acc[i][j][1] + bb.y; v1 = v1 > 0.f ? v1 : 0.f;
            float v2 = acc[i][j][2] + bb.z; v2 = v2 > 0.f ? v2 : 0.f;
            float v3 = acc[i][j][3] + bb.w; v3 = v3 > 0.f ? v3 : 0.f;
            __half2 h0 = __floats2half2_rn(v0, v1);
            __half2 h1 = __floats2half2_rn(v2, v3);
            uint2 o;
            o.x = __builtin_bit_cast(unsigned, h0);
            o.y = __builtin_bit_cast(unsigned, h1);
            *((uint2*)&ldsA[(i * 16 + l16) * LDH + c * 16 + quad * 4]) = o;
        }
    }
    for (int i = t; i < 2048; i += 256) {
        int r = i >> 4, c = i & 15;
        *((uint4*)&ldsW[r * LDH + c * 8]) = *((const uint4*)(w2t + r * 128 + c * 8));
    }
    __syncthreads();

#pragma unroll
    for (int i = 0; i < 4; ++i)
#pragma unroll
        for (int j = 0; j < 2; ++j) acc[i][j] = zero;
    // ---- GEMM2 ----
#pragma unroll
    for (int ks = 0; ks < 4; ++ks) {
        half8 af[4], wf[2];
#pragma unroll
        for (int i = 0; i < 4; ++i)
            af[i] = *((const half8*)&ldsA[(i * 16 + l16) * LDH + ks * 32 + quad * 8]);
#pragma unroll
        for (int j = 0; j < 2; ++j)
            wf[j] = *((const half8*)&ldsW[((ct0 + j) * 16 + l16) * LDH + ks * 32 + quad * 8]);
#pragma unroll
        for (int i = 0; i < 4; ++i)
#pragma unroll
            for (int j = 0; j < 2; ++j)
                acc[i][j] = __builtin_amdgcn_mfma_f32_16x16x32_f16(wf[j], af[i], acc[i][j], 0, 0, 0);
    }
    __syncthreads();
    // epilogue: relu(acc+b2) -> ldsA (fp16)
#pragma unroll
    for (int j = 0; j < 2; ++j) {
        int c = ct0 + j;
        float4 bb = *((const float4*)&ldsB[128 + c * 16 + quad * 4]);
#pragma unroll
        for (int i = 0; i < 4; ++i) {
            float v0 = acc[i][j][0] + bb.x; v0 = v0 > 0.f ? v0 : 0.f;
            float v1 = acc[i][j][1] + bb.y; v1 = v1 > 0.f ? v1 : 0.f;
            float v2 = acc[i][j][2] + bb.z; v2 = v2 > 0.f ? v2 : 0.f;
            float v3 = acc[i][j][3] + bb.w; v3 = v3 > 0.f ? v3 : 0.f;
            __half2 h0 = __floats2half2_rn(v0, v1);
            __half2 h1 = __floats2half2_rn(v2, v3);
            uint2 o;
            o.x = __builtin_bit_cast(unsigned, h0);
            o.y = __builtin_bit_cast(unsigned, h1);
            *((uint2*)&ldsA[(i * 16 + l16) * LDH + c * 16 + quad * 4]) = o;
        }
    }
    __syncthreads();
    for (int i = t; i < 1024; i += 256) {
        int r = i >> 4, c = i & 15;
        int gr = br + r;
        if (gr < N)
            *((uint4*)(out + (size_t)gr * F + c * 8)) = *((const uint4*)&ldsA[r * LDH + c * 8]);
    }
}

// ---------------- mlp2 (MFMA): out = log_softmax(relu(A@w3+b3)@w4+b4) ----------------

__global__ __launch_bounds__(256) void mlp2_mfma_kernel(const __half* __restrict__ A,
        const __half* __restrict__ w3t, const float* __restrict__ b3,
        const __half* __restrict__ w4t, const float* __restrict__ b4,
        float* __restrict__ out, int N) {
    __shared__ __half ldsA[64 * LDH];
    __shared__ __half ldsW[128 * LDH];
    __shared__ float ldsB[176];
    int t = threadIdx.x;
    int wave = t >> 6, lane = t & 63, quad = lane >> 4, l16 = lane & 15;
    int br = blockIdx.x * 64;
    if (t < 128) ldsB[t] = b3[t];
    else if (t < 176) ldsB[t] = (t - 128 < C) ? b4[t - 128] : 0.f;
    for (int i = t; i < 1024; i += 256) {
        int r = i >> 4, c = i & 15;
        int gr = br + r;
        uint4 v = make_uint4(0u, 0u, 0u, 0u);
        if (gr < N) v = *((const uint4*)(A + (size_t)gr * F + c * 8));
        *((uint4*)&ldsA[r * LDH + c * 8]) = v;
    }
    for (int i = t; i < 2048; i += 256) {
        int r = i >> 4, c = i & 15;
        *((uint4*)&ldsW[r * LDH + c * 8]) = *((const uint4*)(w3t + r * 128 + c * 8));
    }
    __syncthreads();

    int ct0 = wave * 2;
    float4v acc[4][2];
    float4v zero = {0.f, 0.f, 0.f, 0.f};
#pragma unroll
    for (int i = 0; i < 4; ++i)
#pragma unroll
        for (int j = 0; j < 2; ++j) acc[i][j] = zero;
    // ---- GEMM3 ----
#pragma unroll
    for (int ks = 0; ks < 4; ++ks) {
        half8 af[4], wf[2];
#pragma unroll
        for (int i = 0; i < 4; ++i)
            af[i] = *((const half8*)&ldsA[(i * 16 + l16) * LDH + ks * 32 + quad * 8]);
#pragma unroll
        for (int j = 0; j < 2; ++j)
            wf[j] = *((const half8*)&ldsW[((ct0 + j) * 16 + l16) * LDH + ks * 32 + quad * 8]);
#pragma unroll
        for (int i = 0; i < 4; ++i)
#pragma unroll
            for (int j = 0; j < 2; ++j)
                acc[i][j] = __builtin_amdgcn_mfma_f32_16x16x32_f16(wf[j], af[i], acc[i][j], 0, 0, 0);
    }
    __syncthreads();
#pragma unroll
    for (int j = 0; j < 2; ++j) {
        int c = ct0 + j;
        float4 bb = *((const float4*)&ldsB[c * 16 + quad * 4]);
#pragma unroll
        for (int i = 0; i < 4; ++i) {
            float v0 = acc[i][j][0] + bb.x; v0 = v0 > 0.f ? v0 : 0.f;
            float v1 = acc[i][j][1] + bb.y; v1 = v1 > 0.f ? v1 : 0.f;
            float v2 = acc[i][j][2] + bb.z; v2 = v2 > 0.f ? v2 : 0.f;
            float v3 = acc[i][j][3] + bb.w; v3 = v3 > 0.f ? v3 : 0.f;
            __half2 h0 = __floats2half2_rn(v0, v1);
            __half2 h1 = __floats2half2_rn(v2, v3);
            uint2 o;
            o.x = __builtin_bit_cast(unsigned, h0);
            o.y = __builtin_bit_cast(unsigned, h1);
            *((uint2*)&ldsA[(i * 16 + l16) * LDH + c * 16 + quad * 4]) = o;
        }
    }
    for (int i = t; i < 768; i += 256) {  // w4t: 48 rows
        int r = i >> 4, c = i & 15;
        *((uint4*)&ldsW[r * LDH + c * 8]) = *((const uint4*)(w4t + r * 128 + c * 8));
    }
    __syncthreads();

    // ---- GEMM4: wave -> node-tile `wave`, col-tiles 0..2 (48 cols, 40 valid) ----
    float4v acc4[3];
#pragma unroll
    for (int c = 0; c < 3; ++c) acc4[c] = zero;
#pragma unroll
    for (int ks = 0; ks < 4; ++ks) {
        half8 af = *((const half8*)&ldsA[(wave * 16 + l16) * LDH + ks * 32 + quad * 8]);
#pragma unroll
        for (int c = 0; c < 3; ++c) {
            half8 wf = *((const half8*)&ldsW[(c * 16 + l16) * LDH + ks * 32 + quad * 8]);
            acc4[c] = __builtin_amdgcn_mfma_f32_16x16x32_f16(wf, af, acc4[c], 0, 0, 0);
        }
    }
    float lv[3][4];
#pragma unroll
    for (int c = 0; c < 3; ++c) {
        float4 bb = *((const float4*)&ldsB[128 + c * 16 + quad * 4]);
        lv[c][0] = acc4[c][0] + bb.x;
        lv[c][1] = acc4[c][1] + bb.y;
        lv[c][2] = acc4[c][2] + bb.z;
        lv[c][3] = acc4[c][3] + bb.w;
    }
    bool tile2ok = (quad < 2);  // cols 32+quad*4..+3 < 40
    float m = -1e30f;
#pragma unroll
    for (int c = 0; c < 3; ++c) {
        if (c == 2 && !tile2ok) continue;
#pragma unroll
        for (int r = 0; r < 4; ++r) m = fmaxf(m, lv[c][r]);
    }
    m = fmaxf(m, __shfl_xor(m, 16));
    m = fmaxf(m, __shfl_xor(m, 32));
    float ssum = 0.f;
#pragma unroll
    for (int c = 0; c < 3; ++c) {
        if (c == 2 && !tile2ok) continue;
#pragma unroll
        for (int r = 0; r < 4; ++r) ssum += __expf(lv[c][r] - m);
    }
    ssum += __shfl_xor(ssum, 16);
    ssum += __shfl_xor(ssum, 32);
    float L = m + __logf(ssum);
    int node = br + wave * 16 + l16;
    if (node < N) {
#pragma unroll
        for (int c = 0; c < 3; ++c) {
            if (c == 2 && !tile2ok) continue;
            float4 o = make_float4(lv[c][0] - L, lv[c][1] - L, lv[c][2] - L, lv[c][3] - L);
            *((float4*)(out + (size_t)node * C + c * 16 + quad * 4)) = o;
        }
    }
}

// ---------------- launch ----------------

extern "C" void kernel_launch(void* const* d_in, const int* in_sizes, int n_in,
                              void* d_out, int out_size, void* d_ws, size_t ws_size,
                              hipStream_t stream) {
    const float* x    = (const float*)d_in[0];
    const int*   ei   = (const int*)d_in[1];
    const float* eps1 = (const float*)d_in[2];
    const float* w1   = (const float*)d_in[3];
    const float* b1   = (const float*)d_in[4];
    const float* w2   = (const float*)d_in[5];
    const float* b2   = (const float*)d_in[6];
    const float* eps2 = (const float*)d_in[7];
    const float* w3   = (const float*)d_in[8];
    const float* b3   = (const float*)d_in[9];
    const float* w4   = (const float*)d_in[10];
    const float* b4   = (const float*)d_in[11];
    float* out = (float*)d_out;

    int N = in_sizes[0] / F;       // 100000
    int E = in_sizes[1] / 2;       // 1600000
    const int* src = ei;
    const int* dst = ei + E;

    int B1 = (N + SCAN_TILE - 1) / SCAN_TILE;

    // workspace layout (halves first, all 16B-aligned)
    __half* x_h  = (__half*)d_ws;                   // N*F
    __half* h0_h = x_h + (size_t)N * F;             // N*F
    __half* h_h  = h0_h + (size_t)N * F;            // N*F
    __half* w1t  = h_h + (size_t)N * F;             // 128*128
    __half* w2t  = w1t + 128 * 128;
    __half* w3t  = w2t + 128 * 128;
    __half* w4t  = w3t + 128 * 128;                 // 48*128
    int* count       = (int*)(w4t + 48 * 128);      // N
    int* row_start   = count + N;                   // N+1
    int* row_pos     = row_start + (N + 1);         // N
    int* src_sorted  = row_pos + N;                 // E
    int* partials    = src_sorted + E;              // 256
    int* partials_ex = partials + 256;              // 256

    // prep: fp16 conversions + weight transposes
    int n4 = N * F / 4;
    conv_f16_kernel<<<(n4 + 255) / 256, 256, 0, stream>>>(x, x_h, n4);
    prep_weights_kernel<<<4, 256, 0, stream>>>(w1, w2, w3, w4, w1t, w2t, w3t, w4t);

    // CSR build
    hipMemsetAsync(count, 0, (size_t)N * sizeof(int), stream);
    hist_kernel<<<(E + 255) / 256, 256, 0, stream>>>(dst, E, count);
    scan_reduce_kernel<<<B1, 256, 0, stream>>>(count, N, partials);
    scan_partials_kernel<<<1, 256, 0, stream>>>(partials, B1, partials_ex, row_start, N, E);
    scan_write_kernel<<<B1, 256, 0, stream>>>(count, N, partials_ex, row_start, row_pos);
    scatter_kernel<<<(E + 255) / 256, 256, 0, stream>>>(src, dst, E, row_pos, src_sorted);

    // layer 1
    agg_f16_kernel<<<(N + 3) / 4, 256, 0, stream>>>(x_h, row_start, src_sorted, eps1, h0_h, N);
    mlp1_mfma_kernel<<<(N + 63) / 64, 256, 0, stream>>>(h0_h, w1t, b1, w2t, b2, h_h, N);
    // layer 2
    agg_f16_kernel<<<(N + 3) / 4, 256, 0, stream>>>(h_h, row_start, src_sorted, eps2, h0_h, N);
    mlp2_mfma_kernel<<<(N + 63) / 64, 256, 0, stream>>>(h0_h, w3t, b3, w4t, b4, out, N);
}